// Round 9
// baseline (709.073 us; speedup 1.0000x reference)
//
#include <hip/hip_runtime.h>
#include <math.h>

#define N_NODES 50000
#define N_EDGES 800000
#define NPAD 50176
// ecsbuf (NPAD+2 ints, ecsbuf[0]=0 forever): counts/prefix/cursor at ecsbuf[1+d].
//   post-scan: start(d) = ecsbuf[1+d];  post-fill: start(d)=ecsbuf[d], end(d)=ecsbuf[d+1]

typedef __attribute__((ext_vector_type(8))) short short8;
typedef __attribute__((ext_vector_type(4))) float f32x4;

// ---------------- CSR build ----------------

__global__ void k_hist(const int* __restrict__ ei, int* __restrict__ deg_out,
                       int* __restrict__ ecsbuf) {
    int e = blockIdx.x * 256 + threadIdx.x;
    if (e < N_EDGES) {
        atomicAdd(&deg_out[ei[e]], 1);
        atomicAdd(&ecsbuf[1 + ei[N_EDGES + e]], 1);
    }
}

__global__ void k_scan1(const int* __restrict__ in, int* __restrict__ out,
                        int* __restrict__ bsum, int n) {
    __shared__ int s[256];
    int i = blockIdx.x * 256 + threadIdx.x;
    int v = (i < n) ? in[i] : 0;
    s[threadIdx.x] = v;
    __syncthreads();
    for (int off = 1; off < 256; off <<= 1) {
        int t = (threadIdx.x >= off) ? s[threadIdx.x - off] : 0;
        __syncthreads();
        s[threadIdx.x] += t;
        __syncthreads();
    }
    if (i < n) out[i] = s[threadIdx.x] - v;   // exclusive
    if (threadIdx.x == 255 && bsum) bsum[blockIdx.x] = s[255];
}

__global__ void k_scan_mid(int* __restrict__ a, int n) {
    __shared__ int s[256];
    __shared__ int carry;
    if (threadIdx.x == 0) carry = 0;
    for (int base = 0; base < n; base += 256) {
        int i = base + threadIdx.x;
        int v = (i < n) ? a[i] : 0;
        s[threadIdx.x] = v;
        __syncthreads();
        for (int off = 1; off < 256; off <<= 1) {
            int t = (threadIdx.x >= off) ? s[threadIdx.x - off] : 0;
            __syncthreads();
            s[threadIdx.x] += t;
            __syncthreads();
        }
        int c = carry;
        if (i < n) a[i] = s[threadIdx.x] - v + c;
        __syncthreads();
        if (threadIdx.x == 0) carry = c + s[255];
        __syncthreads();
    }
}

__global__ void k_scan3(int* __restrict__ out, const int* __restrict__ bscan, int n) {
    int i = blockIdx.x * 256 + threadIdx.x;
    if (i < n) out[i] += bscan[blockIdx.x];
}

__global__ void k_invsqrt(const int* __restrict__ deg_out, const int* __restrict__ ecsbuf,
                          float* __restrict__ inv_out, float* __restrict__ inv_in) {
    int n = blockIdx.x * 256 + threadIdx.x;
    if (n >= N_NODES) return;
    int di = ecsbuf[n + 2] - ecsbuf[n + 1];
    int a = deg_out[n]; if (a < 1) a = 1;
    if (di < 1) di = 1;
    inv_out[n] = 1.0f / sqrtf((float)a);
    inv_in[n]  = 1.0f / sqrtf((float)di);
}

__global__ void k_bucket(const int* __restrict__ ei, int* __restrict__ ecsbuf,
                         int* __restrict__ src_sorted) {
    int e = blockIdx.x * 256 + threadIdx.x;
    if (e < N_EDGES) {
        int s = ei[e], d = ei[N_EDGES + e];
        int p = atomicAdd(&ecsbuf[1 + d], 1);
        src_sorted[p] = s;
    }
}

// ---------------- helpers ----------------

__device__ __forceinline__ float fast_tanh(float x) {
    float e = __expf(2.0f * x);
    float r = __builtin_amdgcn_rcpf(e + 1.0f);
    return 1.0f - 2.0f * r;
}

__device__ __forceinline__ unsigned short rne_bf16(float x) {
    unsigned u = __builtin_bit_cast(unsigned, x);
    return (unsigned short)((u + 0x7FFFu + ((u >> 16) & 1u)) >> 16);
}

__device__ __forceinline__ void split_bf16(float x, unsigned short& hi, unsigned short& lo) {
    hi = rne_bf16(x);
    float hf = __builtin_bit_cast(float, (unsigned)hi << 16);
    lo = rne_bf16(x - hf);
}

__device__ __forceinline__ f32x4 mfma16(short8 a, short8 b, f32x4 c) {
    return __builtin_amdgcn_mfma_f32_16x16x32_bf16(a, b, c, 0, 0, 0);
}

// ---------------- weight split (one launch) ----------------

__device__ __forceinline__ void wsplit_one(const float* __restrict__ W, int KIN, int LDA,
                                           unsigned short* __restrict__ WT_hi,
                                           unsigned short* __restrict__ WT_lo, int idx) {
    int n = idx / LDA;
    int k = idx - n * LDA;
    float v = (n < 220 && k < KIN) ? W[k * 220 + n] : 0.f;
    unsigned short hi, lo;
    split_bf16(v, hi, lo);
    WT_hi[idx] = hi;
    WT_lo[idx] = lo;
}

__global__ void k_wsplit_all(const float* __restrict__ W0, const float* __restrict__ W1,
                             const float* __restrict__ W2,
                             unsigned short* __restrict__ wt0h, unsigned short* __restrict__ wt0l,
                             unsigned short* __restrict__ wt1h, unsigned short* __restrict__ wt1l,
                             unsigned short* __restrict__ wt2h, unsigned short* __restrict__ wt2l) {
    int bx = blockIdx.x;
    if (bx < 28) {
        int idx = bx * 256 + threadIdx.x;          // 224*32 = 7168
        if (idx < 224 * 32) wsplit_one(W0, 22, 32, wt0h, wt0l, idx);
    } else if (bx < 224) {
        int idx = (bx - 28) * 256 + threadIdx.x;   // 224*224 = 50176
        wsplit_one(W1, 220, 224, wt1h, wt1l, idx);
    } else {
        int idx = (bx - 224) * 256 + threadIdx.x;
        wsplit_one(W2, 220, 224, wt2h, wt2l, idx);
    }
}

// ---------------- fused gather -> split-bf16 MFMA GEMM (width 220) ----------------
// Block = 64 dst rows, 4 waves. Wave w gathers rows w*16..+15 (round-8 inner loop,
// branch-free: read-lane clamped to 54), splits sum*inv_in to bf16 hi/lo in a
// WAVE-PRIVATE LDS slab (no barrier: each wave reads only rows it wrote), then
// runs the MFMA body with A from ds_read_b128. LDS stride 232 us -> <=2-way
// bank aliasing on the b128 A-reads (free). Replaces agg220_split + gemm_mfma:
// saves the 90 MB/layer A-buffer round-trip + a launch.
__global__ __launch_bounds__(256, 2) void k_fused220(const float* __restrict__ h,
                                                     const int* __restrict__ ecsbuf,
                                                     const int* __restrict__ srcs,
                                                     const float* __restrict__ inv_in,
                                                     const unsigned short* __restrict__ WT_hi,
                                                     const unsigned short* __restrict__ WT_lo,
                                                     const float* __restrict__ bias,
                                                     const float* __restrict__ post,
                                                     float* __restrict__ out) {
    __shared__ unsigned short sah[64][232];   // 29.0 KB
    __shared__ unsigned short sal[64][232];   // 29.0 KB  (58 KB total -> 2 blocks/CU)
    int tid = threadIdx.x, lane = tid & 63, w = tid >> 6;
    int lrow = lane & 15, q = lane >> 4;
    int rtile = blockIdx.x * 64;
    int rw = w * 16;

    // ---- phase 1: gather + split into wave-private slab
    int f4r = (lane < 55) ? lane * 4 : 216;    // clamped: all lanes load valid addrs
    const float* hb = h + f4r;
    for (int r = 0; r < 16; ++r) {
        int n = rtile + rw + r;
        float4 t = {0.f, 0.f, 0.f, 0.f};
        if (n < N_NODES) {
            int e = ecsbuf[n], end = ecsbuf[n + 1];
            float4 a0 = {0,0,0,0}, a1 = {0,0,0,0}, a2 = {0,0,0,0}, a3 = {0,0,0,0};
            for (; e + 7 < end; e += 8) {
                int s0 = srcs[e],     s1 = srcs[e + 1], s2 = srcs[e + 2], s3 = srcs[e + 3];
                int s4 = srcs[e + 4], s5 = srcs[e + 5], s6 = srcs[e + 6], s7 = srcs[e + 7];
                float4 v0 = *(const float4*)&hb[s0 * 220];
                float4 v1 = *(const float4*)&hb[s1 * 220];
                float4 v2 = *(const float4*)&hb[s2 * 220];
                float4 v3 = *(const float4*)&hb[s3 * 220];
                float4 v4 = *(const float4*)&hb[s4 * 220];
                float4 v5 = *(const float4*)&hb[s5 * 220];
                float4 v6 = *(const float4*)&hb[s6 * 220];
                float4 v7 = *(const float4*)&hb[s7 * 220];
                a0.x += v0.x; a0.y += v0.y; a0.z += v0.z; a0.w += v0.w;
                a1.x += v1.x; a1.y += v1.y; a1.z += v1.z; a1.w += v1.w;
                a2.x += v2.x; a2.y += v2.y; a2.z += v2.z; a2.w += v2.w;
                a3.x += v3.x; a3.y += v3.y; a3.z += v3.z; a3.w += v3.w;
                a0.x += v4.x; a0.y += v4.y; a0.z += v4.z; a0.w += v4.w;
                a1.x += v5.x; a1.y += v5.y; a1.z += v5.z; a1.w += v5.w;
                a2.x += v6.x; a2.y += v6.y; a2.z += v6.z; a2.w += v6.w;
                a3.x += v7.x; a3.y += v7.y; a3.z += v7.z; a3.w += v7.w;
            }
            for (; e + 3 < end; e += 4) {
                int s0 = srcs[e], s1 = srcs[e + 1], s2 = srcs[e + 2], s3 = srcs[e + 3];
                float4 v0 = *(const float4*)&hb[s0 * 220];
                float4 v1 = *(const float4*)&hb[s1 * 220];
                float4 v2 = *(const float4*)&hb[s2 * 220];
                float4 v3 = *(const float4*)&hb[s3 * 220];
                a0.x += v0.x; a0.y += v0.y; a0.z += v0.z; a0.w += v0.w;
                a1.x += v1.x; a1.y += v1.y; a1.z += v1.z; a1.w += v1.w;
                a2.x += v2.x; a2.y += v2.y; a2.z += v2.z; a2.w += v2.w;
                a3.x += v3.x; a3.y += v3.y; a3.z += v3.z; a3.w += v3.w;
            }
            for (; e < end; ++e) {
                float4 v = *(const float4*)&hb[srcs[e] * 220];
                a0.x += v.x; a0.y += v.y; a0.z += v.z; a0.w += v.w;
            }
            float sc = inv_in[n];
            t.x = ((a0.x + a1.x) + (a2.x + a3.x)) * sc;
            t.y = ((a0.y + a1.y) + (a2.y + a3.y)) * sc;
            t.z = ((a0.z + a1.z) + (a2.z + a3.z)) * sc;
            t.w = ((a0.w + a1.w) + (a2.w + a3.w)) * sc;
        }
        if (lane < 55) {
            ushort4 h4, l4;
            split_bf16(t.x, h4.x, l4.x);
            split_bf16(t.y, h4.y, l4.y);
            split_bf16(t.z, h4.z, l4.z);
            split_bf16(t.w, h4.w, l4.w);
            *(ushort4*)&sah[rw + r][lane * 4] = h4;
            *(ushort4*)&sal[rw + r][lane * 4] = l4;
        } else if (lane == 55) {                  // K-pad 220..223
            ushort4 z = {0, 0, 0, 0};
            *(ushort4*)&sah[rw + r][220] = z;
            *(ushort4*)&sal[rw + r][220] = z;
        }
    }
    // no __syncthreads: slab is wave-private

    // ---- phase 2: MFMA (A from LDS, B from global wt planes)
    f32x4 acc[14];
#pragma unroll
    for (int ct = 0; ct < 14; ++ct) acc[ct] = (f32x4){0.f, 0.f, 0.f, 0.f};
#pragma unroll
    for (int ks = 0; ks < 7; ++ks) {
        int k0 = ks * 32 + q * 8;
        short8 ah = *(const short8*)(const void*)&sah[rw + lrow][k0];
        short8 al = *(const short8*)(const void*)&sal[rw + lrow][k0];
#pragma unroll
        for (int ct = 0; ct < 14; ++ct) {
            size_t boff = (size_t)(ct * 16 + lrow) * 224 + k0;
            short8 bh = *(const short8*)(const void*)(WT_hi + boff);
            short8 bl = *(const short8*)(const void*)(WT_lo + boff);
            acc[ct] = mfma16(ah, bh, acc[ct]);
            acc[ct] = mfma16(ah, bl, acc[ct]);
            acc[ct] = mfma16(al, bh, acc[ct]);
        }
    }

    // ---- epilogue: tanh(D + bias) * post
    float pv[4];
#pragma unroll
    for (int r = 0; r < 4; ++r) {
        int row = rtile + rw + q * 4 + r;
        pv[r] = (row < N_NODES) ? post[row] : 0.f;
    }
#pragma unroll
    for (int ct = 0; ct < 14; ++ct) {
        int col = ct * 16 + lrow;
        if (col >= 220) continue;
        float bv = bias[col];
#pragma unroll
        for (int r = 0; r < 4; ++r) {
            int row = rtile + rw + q * 4 + r;
            if (row < N_NODES)
                out[(size_t)row * 220 + col] = pv[r] * fast_tanh(acc[ct][r] + bv);
        }
    }
}

// ---------------- fused layer 0 (width 22, K pad 32) ----------------
__global__ __launch_bounds__(256, 2) void k_fused22(const float* __restrict__ x,
                                                    const float* __restrict__ inv_out,
                                                    const int* __restrict__ ecsbuf,
                                                    const int* __restrict__ srcs,
                                                    const float* __restrict__ inv_in,
                                                    const unsigned short* __restrict__ WT_hi,
                                                    const unsigned short* __restrict__ WT_lo,
                                                    const float* __restrict__ bias,
                                                    const float* __restrict__ post,
                                                    float* __restrict__ out) {
    __shared__ unsigned short sah[64][40];
    __shared__ unsigned short sal[64][40];
    int tid = threadIdx.x, lane = tid & 63, w = tid >> 6;
    int lrow = lane & 15, q = lane >> 4;
    int rtile = blockIdx.x * 64;
    int rw = w * 16;

    int f2r = (lane < 11) ? lane : 10;         // clamped read slot
    const float2* xb = (const float2*)x;
    for (int r = 0; r < 16; ++r) {
        int n = rtile + rw + r;
        float ax = 0.f, ay = 0.f;
        if (n < N_NODES) {
            int e = ecsbuf[n], end = ecsbuf[n + 1];
            for (; e + 3 < end; e += 4) {
                int s0 = srcs[e], s1 = srcs[e + 1], s2 = srcs[e + 2], s3 = srcs[e + 3];
                float c0 = inv_out[s0], c1 = inv_out[s1], c2 = inv_out[s2], c3 = inv_out[s3];
                float2 v0 = xb[s0 * 11 + f2r];
                float2 v1 = xb[s1 * 11 + f2r];
                float2 v2 = xb[s2 * 11 + f2r];
                float2 v3 = xb[s3 * 11 + f2r];
                ax += v0.x * c0 + v1.x * c1 + v2.x * c2 + v3.x * c3;
                ay += v0.y * c0 + v1.y * c1 + v2.y * c2 + v3.y * c3;
            }
            for (; e < end; ++e) {
                int s0 = srcs[e];
                float c0 = inv_out[s0];
                float2 v0 = xb[s0 * 11 + f2r];
                ax += v0.x * c0;
                ay += v0.y * c0;
            }
            float si = inv_in[n];
            ax *= si; ay *= si;
        }
        ushort2 h2, l2;
        split_bf16(ax, h2.x, l2.x);
        split_bf16(ay, h2.y, l2.y);
        if (lane < 11) {
            *(ushort2*)&sah[rw + r][lane * 2] = h2;
            *(ushort2*)&sal[rw + r][lane * 2] = l2;
        } else if (lane < 16) {                 // K-pad 22..31
            ushort2 z = {0, 0};
            *(ushort2*)&sah[rw + r][lane * 2] = z;
            *(ushort2*)&sal[rw + r][lane * 2] = z;
        }
    }
    // no barrier: wave-private slab

    f32x4 acc[14];
#pragma unroll
    for (int ct = 0; ct < 14; ++ct) acc[ct] = (f32x4){0.f, 0.f, 0.f, 0.f};
    {
        short8 ah = *(const short8*)(const void*)&sah[rw + lrow][q * 8];
        short8 al = *(const short8*)(const void*)&sal[rw + lrow][q * 8];
#pragma unroll
        for (int ct = 0; ct < 14; ++ct) {
            size_t boff = (size_t)(ct * 16 + lrow) * 32 + q * 8;
            short8 bh = *(const short8*)(const void*)(WT_hi + boff);
            short8 bl = *(const short8*)(const void*)(WT_lo + boff);
            acc[ct] = mfma16(ah, bh, acc[ct]);
            acc[ct] = mfma16(ah, bl, acc[ct]);
            acc[ct] = mfma16(al, bh, acc[ct]);
        }
    }

    float pv[4];
#pragma unroll
    for (int r = 0; r < 4; ++r) {
        int row = rtile + rw + q * 4 + r;
        pv[r] = (row < N_NODES) ? post[row] : 0.f;
    }
#pragma unroll
    for (int ct = 0; ct < 14; ++ct) {
        int col = ct * 16 + lrow;
        if (col >= 220) continue;
        float bv = bias[col];
#pragma unroll
        for (int r = 0; r < 4; ++r) {
            int row = rtile + rw + q * 4 + r;
            if (row < N_NODES)
                out[(size_t)row * 220 + col] = pv[r] * fast_tanh(acc[ct][r] + bv);
        }
    }
}

// ---------------- layer 3 ----------------

// tmp10 = h @ W3 — thread per node, full row. W3 reads are wave-uniform.
__global__ __launch_bounds__(256) void k_w3(const float* __restrict__ h,
                                            const float* __restrict__ W3,
                                            float* __restrict__ tmp) {
    int n = blockIdx.x * 256 + threadIdx.x;
    if (n >= N_NODES) return;
    float a[10];
#pragma unroll
    for (int j = 0; j < 10; ++j) a[j] = 0.f;
    const float4* hr = (const float4*)&h[(size_t)n * 220];
#pragma unroll 5
    for (int k4 = 0; k4 < 55; ++k4) {
        float4 v = hr[k4];
        const float* wk = &W3[k4 * 40];
#pragma unroll
        for (int j = 0; j < 10; ++j)
            a[j] += v.x * wk[j] + v.y * wk[10 + j] + v.z * wk[20 + j] + v.w * wk[30 + j];
    }
#pragma unroll
    for (int j2 = 0; j2 < 5; ++j2) {
        float2 o = {a[2 * j2], a[2 * j2 + 1]};
        *(float2*)&tmp[(size_t)n * 10 + j2 * 2] = o;
    }
}

// gather tmp10 (2 MB, L2-resident), *inv_in + bias -> d_out
__global__ void k_agg10_epi(const float* __restrict__ tmp, const int* __restrict__ ecsbuf,
                            const int* __restrict__ srcs, const float* __restrict__ inv_in,
                            const float* __restrict__ bias, float* __restrict__ out) {
    int idx = blockIdx.x * 256 + threadIdx.x;
    if (idx >= N_NODES * 5) return;
    int n = idx / 5;
    int f2 = idx - n * 5;
    const float2* tb = (const float2*)(tmp) + f2;
    float ax = 0.f, ay = 0.f;
    int e = ecsbuf[n], end = ecsbuf[n + 1];
    for (; e + 1 < end; e += 2) {
        float2 v0 = tb[srcs[e] * 5];
        float2 v1 = tb[srcs[e + 1] * 5];
        ax += v0.x + v1.x;
        ay += v0.y + v1.y;
    }
    if (e < end) {
        float2 v0 = tb[srcs[e] * 5];
        ax += v0.x;
        ay += v0.y;
    }
    float si = inv_in[n];
    float2 o;
    o.x = ax * si + bias[f2 * 2];
    o.y = ay * si + bias[f2 * 2 + 1];
    *(float2*)&out[n * 10 + f2 * 2] = o;
}

// ---------------- launch ----------------

extern "C" void kernel_launch(void* const* d_in, const int* in_sizes, int n_in,
                              void* d_out, int out_size, void* d_ws, size_t ws_size,
                              hipStream_t stream) {
    const float* x  = (const float*)d_in[0];
    const float* W0 = (const float*)d_in[1];
    const float* b0 = (const float*)d_in[2];
    const float* W1 = (const float*)d_in[3];
    const float* b1 = (const float*)d_in[4];
    const float* W2 = (const float*)d_in[5];
    const float* b2 = (const float*)d_in[6];
    const float* W3 = (const float*)d_in[7];
    const float* b3 = (const float*)d_in[8];
    const int*   ei = (const int*)d_in[9];
    float* out = (float*)d_out;

    int* ws = (int*)d_ws;
    // word offsets (wt1/wt2 = 224*224 ushorts = 25088 WORDS each)
    int* ecsbuf     = ws + 0;               // 50432
    int* deg_out    = ws + 50432;           // 50176
    int* bsumA      = ws + 100608;          // 256 (196 used)
    float* inv_out  = (float*)(ws + 100864);
    float* inv_in   = (float*)(ws + 151040);
    int* src_sorted = ws + 201216;          // 800000
    unsigned short* wt0h = (unsigned short*)(ws + 1001216);   // 3584 w
    unsigned short* wt0l = (unsigned short*)(ws + 1004800);   // 3584 w
    unsigned short* wt1h = (unsigned short*)(ws + 1008384);   // 25088 w
    unsigned short* wt1l = (unsigned short*)(ws + 1033472);   // 25088 w
    unsigned short* wt2h = (unsigned short*)(ws + 1058560);   // 25088 w
    unsigned short* wt2l = (unsigned short*)(ws + 1083648);   // 25088 w
    float* hA = (float*)(ws + 1108736);     // 11001856 w (50000*220 + pad)
    float* hB = (float*)(ws + 12110592);    // 11001856 w -> end 23112448 (92.4 MB)
    float* tmp10 = hB;                      // hB dead after layer 2

    // independent of CSR
    k_wsplit_all<<<420, 256, 0, stream>>>(W0, W1, W2, wt0h, wt0l, wt1h, wt1l, wt2h, wt2l);

    // zero ecsbuf + deg_out (contiguous)
    hipMemsetAsync(ws, 0, (size_t)100608 * sizeof(int), stream);

    k_hist<<<(N_EDGES + 255) / 256, 256, 0, stream>>>(ei, deg_out, ecsbuf);
    k_scan1<<<196, 256, 0, stream>>>(ecsbuf + 1, ecsbuf + 1, bsumA, NPAD);
    k_scan_mid<<<1, 256, 0, stream>>>(bsumA, 196);
    k_scan3<<<196, 256, 0, stream>>>(ecsbuf + 1, bsumA, NPAD);
    k_invsqrt<<<196, 256, 0, stream>>>(deg_out, ecsbuf, inv_out, inv_in);
    k_bucket<<<(N_EDGES + 255) / 256, 256, 0, stream>>>(ei, ecsbuf, src_sorted);

    int fgrid = (N_NODES + 63) / 64;     // 782

    // layer 0: gather x -> LDS split -> MFMA wt0 -> hA (tanh, *inv_out)
    k_fused22<<<fgrid, 256, 0, stream>>>(x, inv_out, ecsbuf, src_sorted, inv_in,
                                         wt0h, wt0l, b0, inv_out, hA);
    // layer 1: hA -> hB
    k_fused220<<<fgrid, 256, 0, stream>>>(hA, ecsbuf, src_sorted, inv_in,
                                          wt1h, wt1l, b1, inv_out, hB);
    // layer 2: hB -> hA
    k_fused220<<<fgrid, 256, 0, stream>>>(hB, ecsbuf, src_sorted, inv_in,
                                          wt2h, wt2l, b2, inv_out, hA);
    // layer 3
    k_w3<<<196, 256, 0, stream>>>(hA, W3, tmp10);
    k_agg10_epi<<<(N_NODES * 5 + 255) / 256, 256, 0, stream>>>(
        tmp10, ecsbuf, src_sorted, inv_in, b3, out);
}

// Round 10
// 631.917 us; speedup vs baseline: 1.1221x; 1.1221x over previous
//
#include <hip/hip_runtime.h>
#include <math.h>

#define N_NODES 50000
#define N_EDGES 800000
#define NPAD 50176
// ecsbuf (NPAD+2 ints, ecsbuf[0]=0): counts live at ecsbuf[1+d] (k_hist),
// post-scan ecsbuf[1+d] = start(d) and is NEVER mutated again (rank-based fill).
// Readers: start(n) = ecsbuf[n+1], end(n) = ecsbuf[n+2].

typedef __attribute__((ext_vector_type(8))) short short8;
typedef __attribute__((ext_vector_type(4))) float f32x4;

// ---------------- CSR build ----------------

// histogram + per-edge rank (rank = arrival index within dst segment)
__global__ void k_hist(const int* __restrict__ ei, int* __restrict__ deg_out,
                       int* __restrict__ ecsbuf, int* __restrict__ rank) {
    int e = blockIdx.x * 256 + threadIdx.x;
    if (e < N_EDGES) {
        atomicAdd(&deg_out[ei[e]], 1);
        rank[e] = atomicAdd(&ecsbuf[1 + ei[N_EDGES + e]], 1);
    }
}

__global__ void k_scan1(const int* __restrict__ in, int* __restrict__ out,
                        int* __restrict__ bsum, int n) {
    __shared__ int s[256];
    int i = blockIdx.x * 256 + threadIdx.x;
    int v = (i < n) ? in[i] : 0;
    s[threadIdx.x] = v;
    __syncthreads();
    for (int off = 1; off < 256; off <<= 1) {
        int t = (threadIdx.x >= off) ? s[threadIdx.x - off] : 0;
        __syncthreads();
        s[threadIdx.x] += t;
        __syncthreads();
    }
    if (i < n) out[i] = s[threadIdx.x] - v;   // exclusive
    if (threadIdx.x == 255 && bsum) bsum[blockIdx.x] = s[255];
}

__global__ void k_scan_mid(int* __restrict__ a, int n) {
    __shared__ int s[256];
    __shared__ int carry;
    if (threadIdx.x == 0) carry = 0;
    for (int base = 0; base < n; base += 256) {
        int i = base + threadIdx.x;
        int v = (i < n) ? a[i] : 0;
        s[threadIdx.x] = v;
        __syncthreads();
        for (int off = 1; off < 256; off <<= 1) {
            int t = (threadIdx.x >= off) ? s[threadIdx.x - off] : 0;
            __syncthreads();
            s[threadIdx.x] += t;
            __syncthreads();
        }
        int c = carry;
        if (i < n) a[i] = s[threadIdx.x] - v + c;
        __syncthreads();
        if (threadIdx.x == 0) carry = c + s[255];
        __syncthreads();
    }
}

__global__ void k_scan3(int* __restrict__ out, const int* __restrict__ bscan, int n) {
    int i = blockIdx.x * 256 + threadIdx.x;
    if (i < n) out[i] += bscan[blockIdx.x];
}

// fused post-scan launch, grid partitioned by blockIdx:
//   [0,196)      invsqrt: inv_out / inv_in per node
//   [196,3321)   bucket fill (ATOMIC-FREE: p = start[d] + rank[e])
//   [3321,5470)  prescale xs = x * rsqrt(max(deg_out,1))  (reads deg_out directly,
//                no dependence on the invsqrt blocks)
__global__ void k_post_scan(const int* __restrict__ ei, const int* __restrict__ ecsbuf,
                            const int* __restrict__ rank, const int* __restrict__ deg_out,
                            const float* __restrict__ x,
                            float* __restrict__ inv_out, float* __restrict__ inv_in,
                            int* __restrict__ src_sorted, float* __restrict__ xs) {
    int bx = blockIdx.x;
    if (bx < 196) {
        int n = bx * 256 + threadIdx.x;
        if (n >= N_NODES) return;
        int di = ecsbuf[n + 2] - ecsbuf[n + 1];
        int a = deg_out[n]; if (a < 1) a = 1;
        if (di < 1) di = 1;
        inv_out[n] = 1.0f / sqrtf((float)a);
        inv_in[n]  = 1.0f / sqrtf((float)di);
    } else if (bx < 3321) {
        int e = (bx - 196) * 256 + threadIdx.x;
        if (e < N_EDGES) {
            int d = ei[N_EDGES + e];
            src_sorted[ecsbuf[1 + d] + rank[e]] = ei[e];
        }
    } else {
        int idx = (bx - 3321) * 256 + threadIdx.x;   // n*11 + f2
        if (idx >= N_NODES * 11) return;
        int n = idx / 11;
        int f2 = idx - n * 11;
        int a = deg_out[n]; if (a < 1) a = 1;
        float sc = 1.0f / sqrtf((float)a);
        float2 v = *(const float2*)&x[n * 22 + f2 * 2];
        v.x *= sc; v.y *= sc;
        *(float2*)&xs[n * 22 + f2 * 2] = v;
    }
}

// ---------------- helpers ----------------

__device__ __forceinline__ float fast_tanh(float x) {
    float e = __expf(2.0f * x);
    float r = __builtin_amdgcn_rcpf(e + 1.0f);
    return 1.0f - 2.0f * r;
}

__device__ __forceinline__ unsigned short rne_bf16(float x) {
    unsigned u = __builtin_bit_cast(unsigned, x);
    return (unsigned short)((u + 0x7FFFu + ((u >> 16) & 1u)) >> 16);
}

__device__ __forceinline__ void split_bf16(float x, unsigned short& hi, unsigned short& lo) {
    hi = rne_bf16(x);
    float hf = __builtin_bit_cast(float, (unsigned)hi << 16);
    lo = rne_bf16(x - hf);
}

__device__ __forceinline__ f32x4 mfma16(short8 a, short8 b, f32x4 c) {
    return __builtin_amdgcn_mfma_f32_16x16x32_bf16(a, b, c, 0, 0, 0);
}

// ---------------- aggregation ----------------

// layer 0: gather pre-scaled xs (width 22), *inv_in, split to bf16 A (K pad 32).
// 16 threads/node; f2 slots 11..15 write zero K-pad. No per-edge scale load.
__global__ void k_agg22_split(const float* __restrict__ xs,
                              const int* __restrict__ ecsbuf, const int* __restrict__ srcs,
                              const float* __restrict__ inv_in,
                              unsigned short* __restrict__ A_hi, unsigned short* __restrict__ A_lo) {
    int idx = blockIdx.x * 256 + threadIdx.x;
    int n = idx >> 4, f2 = idx & 15;
    if (n >= N_NODES) return;
    float ax = 0.f, ay = 0.f;
    if (f2 <= 10) {
        const float2* xb = (const float2*)(xs) + f2;
        int e = ecsbuf[n + 1], end = ecsbuf[n + 2];
        for (; e + 3 < end; e += 4) {
            int s0 = srcs[e], s1 = srcs[e + 1], s2 = srcs[e + 2], s3 = srcs[e + 3];
            float2 v0 = xb[s0 * 11], v1 = xb[s1 * 11];
            float2 v2 = xb[s2 * 11], v3 = xb[s3 * 11];
            ax += (v0.x + v1.x) + (v2.x + v3.x);
            ay += (v0.y + v1.y) + (v2.y + v3.y);
        }
        for (; e < end; ++e) {
            float2 v0 = xb[srcs[e] * 11];
            ax += v0.x;
            ay += v0.y;
        }
        float si = inv_in[n];
        ax *= si; ay *= si;
    }
    ushort2 h2, l2;
    split_bf16(ax, h2.x, l2.x);
    split_bf16(ay, h2.y, l2.y);
    *(ushort2*)&A_hi[n * 32 + f2 * 2] = h2;
    *(ushort2*)&A_lo[n * 32 + f2 * 2] = l2;
}

// width-220 gather + fused (sum*inv_in) -> split bf16 A (stride 224; lane 55 = K-pad).
// One node per 64-lane group; lanes 0..54 own 4 features (float4 row gather).
// 8 independent dwordx4 loads in flight. FETCH ~356 MB = compulsory per-XCD
// first-touch of h (8 x 44 MB); ~110 us is the random-row fetch floor.
__global__ __launch_bounds__(256) void k_agg220_split(const float* __restrict__ h,
                                                      const int* __restrict__ ecsbuf,
                                                      const int* __restrict__ srcs,
                                                      const float* __restrict__ inv_in,
                                                      unsigned short* __restrict__ A_hi,
                                                      unsigned short* __restrict__ A_lo) {
    int lane = threadIdx.x & 63;
    int n = blockIdx.x * 4 + (threadIdx.x >> 6);
    if (n >= N_NODES || lane >= 56) return;   // no barriers; early-exit safe
    size_t ob = (size_t)n * 224 + lane * 4;
    if (lane == 55) {                          // K-pad columns 220..223 = 0
        ushort4 z = {0, 0, 0, 0};
        *(ushort4*)&A_hi[ob] = z;
        *(ushort4*)&A_lo[ob] = z;
        return;
    }
    int f4 = lane * 4;
    const float* hb = h + f4;
    int e = ecsbuf[n + 1], end = ecsbuf[n + 2];
    float4 a0 = {0,0,0,0}, a1 = {0,0,0,0}, a2 = {0,0,0,0}, a3 = {0,0,0,0};
    for (; e + 7 < end; e += 8) {
        int s0 = srcs[e],     s1 = srcs[e + 1], s2 = srcs[e + 2], s3 = srcs[e + 3];
        int s4 = srcs[e + 4], s5 = srcs[e + 5], s6 = srcs[e + 6], s7 = srcs[e + 7];
        float4 v0 = *(const float4*)&hb[s0 * 220];
        float4 v1 = *(const float4*)&hb[s1 * 220];
        float4 v2 = *(const float4*)&hb[s2 * 220];
        float4 v3 = *(const float4*)&hb[s3 * 220];
        float4 v4 = *(const float4*)&hb[s4 * 220];
        float4 v5 = *(const float4*)&hb[s5 * 220];
        float4 v6 = *(const float4*)&hb[s6 * 220];
        float4 v7 = *(const float4*)&hb[s7 * 220];
        a0.x += v0.x; a0.y += v0.y; a0.z += v0.z; a0.w += v0.w;
        a1.x += v1.x; a1.y += v1.y; a1.z += v1.z; a1.w += v1.w;
        a2.x += v2.x; a2.y += v2.y; a2.z += v2.z; a2.w += v2.w;
        a3.x += v3.x; a3.y += v3.y; a3.z += v3.z; a3.w += v3.w;
        a0.x += v4.x; a0.y += v4.y; a0.z += v4.z; a0.w += v4.w;
        a1.x += v5.x; a1.y += v5.y; a1.z += v5.z; a1.w += v5.w;
        a2.x += v6.x; a2.y += v6.y; a2.z += v6.z; a2.w += v6.w;
        a3.x += v7.x; a3.y += v7.y; a3.z += v7.z; a3.w += v7.w;
    }
    for (; e + 3 < end; e += 4) {
        int s0 = srcs[e], s1 = srcs[e + 1], s2 = srcs[e + 2], s3 = srcs[e + 3];
        float4 v0 = *(const float4*)&hb[s0 * 220];
        float4 v1 = *(const float4*)&hb[s1 * 220];
        float4 v2 = *(const float4*)&hb[s2 * 220];
        float4 v3 = *(const float4*)&hb[s3 * 220];
        a0.x += v0.x; a0.y += v0.y; a0.z += v0.z; a0.w += v0.w;
        a1.x += v1.x; a1.y += v1.y; a1.z += v1.z; a1.w += v1.w;
        a2.x += v2.x; a2.y += v2.y; a2.z += v2.z; a2.w += v2.w;
        a3.x += v3.x; a3.y += v3.y; a3.z += v3.z; a3.w += v3.w;
    }
    for (; e < end; ++e) {
        float4 v = *(const float4*)&hb[srcs[e] * 220];
        a0.x += v.x; a0.y += v.y; a0.z += v.z; a0.w += v.w;
    }
    float sc = inv_in[n];
    float4 t;
    t.x = ((a0.x + a1.x) + (a2.x + a3.x)) * sc;
    t.y = ((a0.y + a1.y) + (a2.y + a3.y)) * sc;
    t.z = ((a0.z + a1.z) + (a2.z + a3.z)) * sc;
    t.w = ((a0.w + a1.w) + (a2.w + a3.w)) * sc;
    ushort4 h4, l4;
    split_bf16(t.x, h4.x, l4.x);
    split_bf16(t.y, h4.y, l4.y);
    split_bf16(t.z, h4.z, l4.z);
    split_bf16(t.w, h4.w, l4.w);
    *(ushort4*)&A_hi[ob] = h4;
    *(ushort4*)&A_lo[ob] = l4;
}

// layer 3: gather tmp10 (width 10, 2 MB -> L2-resident), *inv_in + bias -> d_out
__global__ void k_agg10_epi(const float* __restrict__ tmp, const int* __restrict__ ecsbuf,
                            const int* __restrict__ srcs, const float* __restrict__ inv_in,
                            const float* __restrict__ bias, float* __restrict__ out) {
    int idx = blockIdx.x * 256 + threadIdx.x;
    if (idx >= N_NODES * 5) return;
    int n = idx / 5;
    int f2 = idx - n * 5;
    const float2* tb = (const float2*)(tmp) + f2;
    float ax = 0.f, ay = 0.f;
    int e = ecsbuf[n + 1], end = ecsbuf[n + 2];
    for (; e + 1 < end; e += 2) {
        float2 v0 = tb[srcs[e] * 5];
        float2 v1 = tb[srcs[e + 1] * 5];
        ax += v0.x + v1.x;
        ay += v0.y + v1.y;
    }
    if (e < end) {
        float2 v0 = tb[srcs[e] * 5];
        ax += v0.x;
        ay += v0.y;
    }
    float si = inv_in[n];
    float2 o;
    o.x = ax * si + bias[f2 * 2];
    o.y = ay * si + bias[f2 * 2 + 1];
    *(float2*)&out[n * 10 + f2 * 2] = o;
}

// ---------------- weight split (one launch) ----------------

__device__ __forceinline__ void wsplit_one(const float* __restrict__ W, int KIN, int LDA,
                                           unsigned short* __restrict__ WT_hi,
                                           unsigned short* __restrict__ WT_lo, int idx) {
    int n = idx / LDA;
    int k = idx - n * LDA;
    float v = (n < 220 && k < KIN) ? W[k * 220 + n] : 0.f;
    unsigned short hi, lo;
    split_bf16(v, hi, lo);
    WT_hi[idx] = hi;
    WT_lo[idx] = lo;
}

__global__ void k_wsplit_all(const float* __restrict__ W0, const float* __restrict__ W1,
                             const float* __restrict__ W2,
                             unsigned short* __restrict__ wt0h, unsigned short* __restrict__ wt0l,
                             unsigned short* __restrict__ wt1h, unsigned short* __restrict__ wt1l,
                             unsigned short* __restrict__ wt2h, unsigned short* __restrict__ wt2l) {
    int bx = blockIdx.x;
    if (bx < 28) {
        int idx = bx * 256 + threadIdx.x;          // 224*32 = 7168
        if (idx < 224 * 32) wsplit_one(W0, 22, 32, wt0h, wt0l, idx);
    } else if (bx < 224) {
        int idx = (bx - 28) * 256 + threadIdx.x;   // 224*224 = 50176
        wsplit_one(W1, 220, 224, wt1h, wt1l, idx);
    } else {
        int idx = (bx - 224) * 256 + threadIdx.x;
        wsplit_one(W2, 220, 224, wt2h, wt2l, idx);
    }
}

// ---------------- MFMA split-bf16 GEMM ----------------
// D = A@W via A_hi*W_hi + A_hi*W_lo + A_lo*W_hi (~fp32 precision).
// out[n][j] = post[n] * tanh(D + bias); inv_in pre-folded into A.
template <int KSTEPS, int LDA>
__global__ __launch_bounds__(256) void k_gemm_mfma(const unsigned short* __restrict__ A_hi,
                                                   const unsigned short* __restrict__ A_lo,
                                                   const unsigned short* __restrict__ WT_hi,
                                                   const unsigned short* __restrict__ WT_lo,
                                                   const float* __restrict__ bias,
                                                   const float* __restrict__ post,
                                                   float* __restrict__ out) {
    int tid = threadIdx.x;
    int l = tid & 63, w = tid >> 6;
    int lrow = l & 15, q = l >> 4;
    int rtile = blockIdx.x * 64 + w * 16;

    const unsigned short* pah = A_hi + (size_t)(rtile + lrow) * LDA + q * 8;
    const unsigned short* pal = A_lo + (size_t)(rtile + lrow) * LDA + q * 8;

    f32x4 acc[14];
#pragma unroll
    for (int ct = 0; ct < 14; ++ct) acc[ct] = (f32x4){0.f, 0.f, 0.f, 0.f};

#pragma unroll
    for (int ks = 0; ks < KSTEPS; ++ks) {
        int k0 = ks * 32;
        short8 ah = *(const short8*)(const void*)(pah + k0);
        short8 al = *(const short8*)(const void*)(pal + k0);
#pragma unroll
        for (int ct = 0; ct < 14; ++ct) {
            size_t boff = (size_t)(ct * 16 + lrow) * LDA + q * 8 + k0;
            short8 bh = *(const short8*)(const void*)(WT_hi + boff);
            short8 bl = *(const short8*)(const void*)(WT_lo + boff);
            acc[ct] = mfma16(ah, bh, acc[ct]);
            acc[ct] = mfma16(ah, bl, acc[ct]);
            acc[ct] = mfma16(al, bh, acc[ct]);
        }
    }

    float pv[4];
#pragma unroll
    for (int r = 0; r < 4; ++r) {
        int row = rtile + q * 4 + r;
        pv[r] = (row < N_NODES) ? post[row] : 0.f;
    }
#pragma unroll
    for (int ct = 0; ct < 14; ++ct) {
        int col = ct * 16 + lrow;
        if (col >= 220) continue;
        float bv = bias[col];
#pragma unroll
        for (int r = 0; r < 4; ++r) {
            int row = rtile + q * 4 + r;
            if (row < N_NODES)
                out[(size_t)row * 220 + col] = pv[r] * fast_tanh(acc[ct][r] + bv);
        }
    }
}

// tmp10 = h @ W3 — thread per node, full row. W3 reads are wave-uniform.
__global__ __launch_bounds__(256) void k_w3(const float* __restrict__ h,
                                            const float* __restrict__ W3,
                                            float* __restrict__ tmp) {
    int n = blockIdx.x * 256 + threadIdx.x;
    if (n >= N_NODES) return;
    float a[10];
#pragma unroll
    for (int j = 0; j < 10; ++j) a[j] = 0.f;
    const float4* hr = (const float4*)&h[(size_t)n * 220];
#pragma unroll 5
    for (int k4 = 0; k4 < 55; ++k4) {
        float4 v = hr[k4];
        const float* wk = &W3[k4 * 40];
#pragma unroll
        for (int j = 0; j < 10; ++j)
            a[j] += v.x * wk[j] + v.y * wk[10 + j] + v.z * wk[20 + j] + v.w * wk[30 + j];
    }
#pragma unroll
    for (int j2 = 0; j2 < 5; ++j2) {
        float2 o = {a[2 * j2], a[2 * j2 + 1]};
        *(float2*)&tmp[(size_t)n * 10 + j2 * 2] = o;
    }
}

// ---------------- launch ----------------

extern "C" void kernel_launch(void* const* d_in, const int* in_sizes, int n_in,
                              void* d_out, int out_size, void* d_ws, size_t ws_size,
                              hipStream_t stream) {
    const float* x  = (const float*)d_in[0];
    const float* W0 = (const float*)d_in[1];
    const float* b0 = (const float*)d_in[2];
    const float* W1 = (const float*)d_in[3];
    const float* b1 = (const float*)d_in[4];
    const float* W2 = (const float*)d_in[5];
    const float* b2 = (const float*)d_in[6];
    const float* W3 = (const float*)d_in[7];
    const float* b3 = (const float*)d_in[8];
    const int*   ei = (const int*)d_in[9];
    float* out = (float*)d_out;

    int* ws = (int*)d_ws;
    // word offsets (wt1/wt2 = 224*224 ushorts = 25088 WORDS each)
    int* ecsbuf     = ws + 0;               // 50432 (50178 used; [0]=0)
    int* deg_out    = ws + 50432;           // 50176
    int* bsumA      = ws + 100608;          // 256 (196 used)
    float* inv_out  = (float*)(ws + 100864);
    float* inv_in   = (float*)(ws + 151040);
    int* src_sorted = ws + 201216;          // 800000
    unsigned short* wt0h = (unsigned short*)(ws + 1001216);   // 3584 w
    unsigned short* wt0l = (unsigned short*)(ws + 1004800);   // 3584 w
    unsigned short* wt1h = (unsigned short*)(ws + 1008384);   // 25088 w
    unsigned short* wt1l = (unsigned short*)(ws + 1033472);   // 25088 w
    unsigned short* wt2h = (unsigned short*)(ws + 1058560);   // 25088 w
    unsigned short* wt2l = (unsigned short*)(ws + 1083648);   // 25088 w
    unsigned short* ahi  = (unsigned short*)(ws + 1108736);   // 5619712 w
    unsigned short* alo  = (unsigned short*)(ws + 6728448);   // 5619712 w
    float* hbuf  = (float*)(ws + 12348160); // 11000000 w
    float* xs    = (float*)(ws + 23348160); // 1100032 w -> end 24448192 (97.8 MB)
    // aliases: rank lives in ahi's slot (dead before ahi first written);
    // tmp10 in ahi too (layer 3, ahi dead by then)
    int* rank    = (int*)ahi;
    float* tmp10 = (float*)ahi;

    // independent of CSR
    k_wsplit_all<<<420, 256, 0, stream>>>(W0, W1, W2, wt0h, wt0l, wt1h, wt1l, wt2h, wt2l);

    // zero ecsbuf + deg_out (contiguous)
    hipMemsetAsync(ws, 0, (size_t)100608 * sizeof(int), stream);

    // CSR: hist(+rank) -> scan -> fused{invsqrt | atomic-free fill | prescale-x}
    k_hist<<<(N_EDGES + 255) / 256, 256, 0, stream>>>(ei, deg_out, ecsbuf, rank);
    k_scan1<<<196, 256, 0, stream>>>(ecsbuf + 1, ecsbuf + 1, bsumA, NPAD);
    k_scan_mid<<<1, 256, 0, stream>>>(bsumA, 196);
    k_scan3<<<196, 256, 0, stream>>>(ecsbuf + 1, bsumA, NPAD);
    k_post_scan<<<5470, 256, 0, stream>>>(ei, ecsbuf, rank, deg_out, x,
                                          inv_out, inv_in, src_sorted, xs);

    int mfma_grid = (N_NODES + 63) / 64;     // 782
    int agg_grid  = (N_NODES + 3) / 4;       // 12500

    // ---- layer 0
    k_agg22_split<<<(N_NODES * 16 + 255) / 256, 256, 0, stream>>>(
        xs, ecsbuf, src_sorted, inv_in, ahi, alo);
    k_gemm_mfma<1, 32><<<mfma_grid, 256, 0, stream>>>(ahi, alo, wt0h, wt0l, b0, inv_out, hbuf);

    // ---- layer 1
    k_agg220_split<<<agg_grid, 256, 0, stream>>>(hbuf, ecsbuf, src_sorted, inv_in, ahi, alo);
    k_gemm_mfma<7, 224><<<mfma_grid, 256, 0, stream>>>(ahi, alo, wt1h, wt1l, b1, inv_out, hbuf);

    // ---- layer 2
    k_agg220_split<<<agg_grid, 256, 0, stream>>>(hbuf, ecsbuf, src_sorted, inv_in, ahi, alo);
    k_gemm_mfma<7, 224><<<mfma_grid, 256, 0, stream>>>(ahi, alo, wt2h, wt2l, b2, inv_out, hbuf);

    // ---- layer 3
    k_w3<<<196, 256, 0, stream>>>(hbuf, W3, tmp10);
    k_agg10_epi<<<(N_NODES * 5 + 255) / 256, 256, 0, stream>>>(
        tmp10, ecsbuf, src_sorted, inv_in, b3, out);
}

// Round 11
// 559.078 us; speedup vs baseline: 1.2683x; 1.1303x over previous
//
#include <hip/hip_runtime.h>
#include <math.h>

#define N_NODES 50000
#define N_EDGES 800000
#define NPAD 50176
#define HSTR 224   // hbuf row stride (floats): 14 aligned cachelines, no straddle
// ecsbuf (NPAD+2 ints, ecsbuf[0]=0): counts at ecsbuf[1+d] (k_hist); post-scan
// ecsbuf[1+d] = start(d), never mutated again (rank-based fill).
// Readers: start(n) = ecsbuf[n+1], end(n) = ecsbuf[n+2].

typedef __attribute__((ext_vector_type(8))) short short8;
typedef __attribute__((ext_vector_type(4))) float f32x4;

// ---------------- helpers ----------------

__device__ __forceinline__ float fast_tanh(float x) {
    float e = __expf(2.0f * x);
    float r = __builtin_amdgcn_rcpf(e + 1.0f);
    return 1.0f - 2.0f * r;
}

__device__ __forceinline__ unsigned short rne_bf16(float x) {
    unsigned u = __builtin_bit_cast(unsigned, x);
    return (unsigned short)((u + 0x7FFFu + ((u >> 16) & 1u)) >> 16);
}

__device__ __forceinline__ void split_bf16(float x, unsigned short& hi, unsigned short& lo) {
    hi = rne_bf16(x);
    float hf = __builtin_bit_cast(float, (unsigned)hi << 16);
    lo = rne_bf16(x - hf);
}

__device__ __forceinline__ f32x4 mfma16(short8 a, short8 b, f32x4 c) {
    return __builtin_amdgcn_mfma_f32_16x16x32_bf16(a, b, c, 0, 0, 0);
}

__device__ __forceinline__ void wsplit_one(const float* __restrict__ W, int KIN, int LDA,
                                           unsigned short* __restrict__ WT_hi,
                                           unsigned short* __restrict__ WT_lo, int idx) {
    int n = idx / LDA;
    int k = idx - n * LDA;
    float v = (n < 220 && k < KIN) ? W[k * 220 + n] : 0.f;
    unsigned short hi, lo;
    split_bf16(v, hi, lo);
    WT_hi[idx] = hi;
    WT_lo[idx] = lo;
}

// ---------------- CSR build ----------------

// partitioned launch: [0,3125) histogram + per-edge rank; [3125,3545) weight splits
__global__ void k_hist_wsplit(const int* __restrict__ ei, int* __restrict__ deg_out,
                              int* __restrict__ ecsbuf, int* __restrict__ rank,
                              const float* __restrict__ W0, const float* __restrict__ W1,
                              const float* __restrict__ W2,
                              unsigned short* __restrict__ wt0h, unsigned short* __restrict__ wt0l,
                              unsigned short* __restrict__ wt1h, unsigned short* __restrict__ wt1l,
                              unsigned short* __restrict__ wt2h, unsigned short* __restrict__ wt2l) {
    int bx = blockIdx.x;
    if (bx < 3125) {
        int e = bx * 256 + threadIdx.x;
        if (e < N_EDGES) {
            atomicAdd(&deg_out[ei[e]], 1);
            rank[e] = atomicAdd(&ecsbuf[1 + ei[N_EDGES + e]], 1);
        }
    } else if (bx < 3153) {
        int idx = (bx - 3125) * 256 + threadIdx.x;          // 224*32 = 7168
        if (idx < 224 * 32) wsplit_one(W0, 22, 32, wt0h, wt0l, idx);
    } else if (bx < 3349) {
        int idx = (bx - 3153) * 256 + threadIdx.x;          // 224*224 = 50176
        wsplit_one(W1, 220, 224, wt1h, wt1l, idx);
    } else {
        int idx = (bx - 3349) * 256 + threadIdx.x;
        wsplit_one(W2, 220, 224, wt2h, wt2l, idx);
    }
}

__global__ void k_scan1(const int* __restrict__ in, int* __restrict__ out,
                        int* __restrict__ bsum, int n) {
    __shared__ int s[256];
    int i = blockIdx.x * 256 + threadIdx.x;
    int v = (i < n) ? in[i] : 0;
    s[threadIdx.x] = v;
    __syncthreads();
    for (int off = 1; off < 256; off <<= 1) {
        int t = (threadIdx.x >= off) ? s[threadIdx.x - off] : 0;
        __syncthreads();
        s[threadIdx.x] += t;
        __syncthreads();
    }
    if (i < n) out[i] = s[threadIdx.x] - v;   // exclusive
    if (threadIdx.x == 255 && bsum) bsum[blockIdx.x] = s[255];
}

__global__ void k_scan_mid(int* __restrict__ a, int n) {
    __shared__ int s[256];
    __shared__ int carry;
    if (threadIdx.x == 0) carry = 0;
    for (int base = 0; base < n; base += 256) {
        int i = base + threadIdx.x;
        int v = (i < n) ? a[i] : 0;
        s[threadIdx.x] = v;
        __syncthreads();
        for (int off = 1; off < 256; off <<= 1) {
            int t = (threadIdx.x >= off) ? s[threadIdx.x - off] : 0;
            __syncthreads();
            s[threadIdx.x] += t;
            __syncthreads();
        }
        int c = carry;
        if (i < n) a[i] = s[threadIdx.x] - v + c;
        __syncthreads();
        if (threadIdx.x == 0) carry = c + s[255];
        __syncthreads();
    }
}

__global__ void k_scan3(int* __restrict__ out, const int* __restrict__ bscan, int n) {
    int i = blockIdx.x * 256 + threadIdx.x;
    if (i < n) out[i] += bscan[blockIdx.x];
}

// fused post-scan: [0,196) invsqrt | [196,3321) atomic-free fill | [3321,5470) prescale xs
__global__ void k_post_scan(const int* __restrict__ ei, const int* __restrict__ ecsbuf,
                            const int* __restrict__ rank, const int* __restrict__ deg_out,
                            const float* __restrict__ x,
                            float* __restrict__ inv_out, float* __restrict__ inv_in,
                            int* __restrict__ src_sorted, float* __restrict__ xs) {
    int bx = blockIdx.x;
    if (bx < 196) {
        int n = bx * 256 + threadIdx.x;
        if (n >= N_NODES) return;
        int di = ecsbuf[n + 2] - ecsbuf[n + 1];
        int a = deg_out[n]; if (a < 1) a = 1;
        if (di < 1) di = 1;
        inv_out[n] = 1.0f / sqrtf((float)a);
        inv_in[n]  = 1.0f / sqrtf((float)di);
    } else if (bx < 3321) {
        int e = (bx - 196) * 256 + threadIdx.x;
        if (e < N_EDGES) {
            int d = ei[N_EDGES + e];
            src_sorted[ecsbuf[1 + d] + rank[e]] = ei[e];
        }
    } else {
        int idx = (bx - 3321) * 256 + threadIdx.x;   // n*11 + f2
        if (idx >= N_NODES * 11) return;
        int n = idx / 11;
        int f2 = idx - n * 11;
        int a = deg_out[n]; if (a < 1) a = 1;
        float sc = 1.0f / sqrtf((float)a);
        float2 v = *(const float2*)&x[n * 22 + f2 * 2];
        v.x *= sc; v.y *= sc;
        *(float2*)&xs[n * 22 + f2 * 2] = v;
    }
}

// ---------------- aggregation ----------------

// layer 0: gather pre-scaled xs (width 22), *inv_in, split to bf16 A (K pad 32).
__global__ void k_agg22_split(const float* __restrict__ xs,
                              const int* __restrict__ ecsbuf, const int* __restrict__ srcs,
                              const float* __restrict__ inv_in,
                              unsigned short* __restrict__ A_hi, unsigned short* __restrict__ A_lo) {
    int idx = blockIdx.x * 256 + threadIdx.x;
    int n = idx >> 4, f2 = idx & 15;
    if (n >= N_NODES) return;
    float ax = 0.f, ay = 0.f;
    if (f2 <= 10) {
        const float2* xb = (const float2*)(xs) + f2;
        int e = ecsbuf[n + 1], end = ecsbuf[n + 2];
        for (; e + 3 < end; e += 4) {
            int s0 = srcs[e], s1 = srcs[e + 1], s2 = srcs[e + 2], s3 = srcs[e + 3];
            float2 v0 = xb[s0 * 11], v1 = xb[s1 * 11];
            float2 v2 = xb[s2 * 11], v3 = xb[s3 * 11];
            ax += (v0.x + v1.x) + (v2.x + v3.x);
            ay += (v0.y + v1.y) + (v2.y + v3.y);
        }
        for (; e < end; ++e) {
            float2 v0 = xb[srcs[e] * 11];
            ax += v0.x;
            ay += v0.y;
        }
        float si = inv_in[n];
        ax *= si; ay *= si;
    }
    ushort2 h2, l2;
    split_bf16(ax, h2.x, l2.x);
    split_bf16(ay, h2.y, l2.y);
    *(ushort2*)&A_hi[n * 32 + f2 * 2] = h2;
    *(ushort2*)&A_lo[n * 32 + f2 * 2] = l2;
}

// width-220 gather (h stride 224 = aligned 14-line rows) + *inv_in -> split bf16 A.
// One node per 64-lane group; lanes 0..54 own 4 features; 8 loads in flight.
// ~109 us / 356 MB FETCH = compulsory per-XCD first-touch floor (measured r8/r10).
__global__ __launch_bounds__(256) void k_agg220_split(const float* __restrict__ h,
                                                      const int* __restrict__ ecsbuf,
                                                      const int* __restrict__ srcs,
                                                      const float* __restrict__ inv_in,
                                                      unsigned short* __restrict__ A_hi,
                                                      unsigned short* __restrict__ A_lo) {
    int lane = threadIdx.x & 63;
    int n = blockIdx.x * 4 + (threadIdx.x >> 6);
    if (n >= N_NODES || lane >= 56) return;   // no barriers; early-exit safe
    size_t ob = (size_t)n * 224 + lane * 4;
    if (lane == 55) {                          // K-pad columns 220..223 = 0
        ushort4 z = {0, 0, 0, 0};
        *(ushort4*)&A_hi[ob] = z;
        *(ushort4*)&A_lo[ob] = z;
        return;
    }
    int f4 = lane * 4;
    const float* hb = h + f4;
    int e = ecsbuf[n + 1], end = ecsbuf[n + 2];
    float4 a0 = {0,0,0,0}, a1 = {0,0,0,0}, a2 = {0,0,0,0}, a3 = {0,0,0,0};
    for (; e + 7 < end; e += 8) {
        int s0 = srcs[e],     s1 = srcs[e + 1], s2 = srcs[e + 2], s3 = srcs[e + 3];
        int s4 = srcs[e + 4], s5 = srcs[e + 5], s6 = srcs[e + 6], s7 = srcs[e + 7];
        float4 v0 = *(const float4*)&hb[s0 * HSTR];
        float4 v1 = *(const float4*)&hb[s1 * HSTR];
        float4 v2 = *(const float4*)&hb[s2 * HSTR];
        float4 v3 = *(const float4*)&hb[s3 * HSTR];
        float4 v4 = *(const float4*)&hb[s4 * HSTR];
        float4 v5 = *(const float4*)&hb[s5 * HSTR];
        float4 v6 = *(const float4*)&hb[s6 * HSTR];
        float4 v7 = *(const float4*)&hb[s7 * HSTR];
        a0.x += v0.x; a0.y += v0.y; a0.z += v0.z; a0.w += v0.w;
        a1.x += v1.x; a1.y += v1.y; a1.z += v1.z; a1.w += v1.w;
        a2.x += v2.x; a2.y += v2.y; a2.z += v2.z; a2.w += v2.w;
        a3.x += v3.x; a3.y += v3.y; a3.z += v3.z; a3.w += v3.w;
        a0.x += v4.x; a0.y += v4.y; a0.z += v4.z; a0.w += v4.w;
        a1.x += v5.x; a1.y += v5.y; a1.z += v5.z; a1.w += v5.w;
        a2.x += v6.x; a2.y += v6.y; a2.z += v6.z; a2.w += v6.w;
        a3.x += v7.x; a3.y += v7.y; a3.z += v7.z; a3.w += v7.w;
    }
    for (; e + 3 < end; e += 4) {
        int s0 = srcs[e], s1 = srcs[e + 1], s2 = srcs[e + 2], s3 = srcs[e + 3];
        float4 v0 = *(const float4*)&hb[s0 * HSTR];
        float4 v1 = *(const float4*)&hb[s1 * HSTR];
        float4 v2 = *(const float4*)&hb[s2 * HSTR];
        float4 v3 = *(const float4*)&hb[s3 * HSTR];
        a0.x += v0.x; a0.y += v0.y; a0.z += v0.z; a0.w += v0.w;
        a1.x += v1.x; a1.y += v1.y; a1.z += v1.z; a1.w += v1.w;
        a2.x += v2.x; a2.y += v2.y; a2.z += v2.z; a2.w += v2.w;
        a3.x += v3.x; a3.y += v3.y; a3.z += v3.z; a3.w += v3.w;
    }
    for (; e < end; ++e) {
        float4 v = *(const float4*)&hb[srcs[e] * HSTR];
        a0.x += v.x; a0.y += v.y; a0.z += v.z; a0.w += v.w;
    }
    float sc = inv_in[n];
    float4 t;
    t.x = ((a0.x + a1.x) + (a2.x + a3.x)) * sc;
    t.y = ((a0.y + a1.y) + (a2.y + a3.y)) * sc;
    t.z = ((a0.z + a1.z) + (a2.z + a3.z)) * sc;
    t.w = ((a0.w + a1.w) + (a2.w + a3.w)) * sc;
    ushort4 h4, l4;
    split_bf16(t.x, h4.x, l4.x);
    split_bf16(t.y, h4.y, l4.y);
    split_bf16(t.z, h4.z, l4.z);
    split_bf16(t.w, h4.w, l4.w);
    *(ushort4*)&A_hi[ob] = h4;
    *(ushort4*)&A_lo[ob] = l4;
}

// layer 3: gather tmp10 (width 10, 2 MB -> L2-resident), *inv_in + bias -> d_out
__global__ void k_agg10_epi(const float* __restrict__ tmp, const int* __restrict__ ecsbuf,
                            const int* __restrict__ srcs, const float* __restrict__ inv_in,
                            const float* __restrict__ bias, float* __restrict__ out) {
    int idx = blockIdx.x * 256 + threadIdx.x;
    if (idx >= N_NODES * 5) return;
    int n = idx / 5;
    int f2 = idx - n * 5;
    const float2* tb = (const float2*)(tmp) + f2;
    float ax = 0.f, ay = 0.f;
    int e = ecsbuf[n + 1], end = ecsbuf[n + 2];
    for (; e + 1 < end; e += 2) {
        float2 v0 = tb[srcs[e] * 5];
        float2 v1 = tb[srcs[e + 1] * 5];
        ax += v0.x + v1.x;
        ay += v0.y + v1.y;
    }
    if (e < end) {
        float2 v0 = tb[srcs[e] * 5];
        ax += v0.x;
        ay += v0.y;
    }
    float si = inv_in[n];
    float2 o;
    o.x = ax * si + bias[f2 * 2];
    o.y = ay * si + bias[f2 * 2 + 1];
    *(float2*)&out[n * 10 + f2 * 2] = o;
}

// ---------------- MFMA split-bf16 GEMM, 2 row-tiles per wave ----------------
// D = A@W via A_hi*W_hi + A_hi*W_lo + A_lo*W_hi (~fp32 precision).
// Wave computes 32 rows (two 16-row MFMA tiles) sharing B fragments: halves the
// 613 MB/GEMM L2 B-read stream of the 1-tile version, 6 MFMA per bh/bl pair.
// acc = 2x14 f32x4 = 112 VGPR (below the r3 spill cliff; no min-wave bound).
// out stride HSTR; rows >= N_NODES masked (A rows 50000..50175 are poison but
// row-local in D, never stored).
template <int KSTEPS, int LDA>
__global__ __launch_bounds__(256) void k_gemm_mfma(const unsigned short* __restrict__ A_hi,
                                                   const unsigned short* __restrict__ A_lo,
                                                   const unsigned short* __restrict__ WT_hi,
                                                   const unsigned short* __restrict__ WT_lo,
                                                   const float* __restrict__ bias,
                                                   const float* __restrict__ post,
                                                   float* __restrict__ out) {
    int tid = threadIdx.x;
    int l = tid & 63, w = tid >> 6;
    int lrow = l & 15, q = l >> 4;
    int rt = blockIdx.x * 128 + w * 32;

    const unsigned short* pa0h = A_hi + (size_t)(rt + lrow) * LDA + q * 8;
    const unsigned short* pa0l = A_lo + (size_t)(rt + lrow) * LDA + q * 8;
    const unsigned short* pa1h = pa0h + 16 * LDA;
    const unsigned short* pa1l = pa0l + 16 * LDA;

    f32x4 acc0[14], acc1[14];
#pragma unroll
    for (int ct = 0; ct < 14; ++ct) {
        acc0[ct] = (f32x4){0.f, 0.f, 0.f, 0.f};
        acc1[ct] = (f32x4){0.f, 0.f, 0.f, 0.f};
    }

#pragma unroll
    for (int ks = 0; ks < KSTEPS; ++ks) {
        int k0 = ks * 32;
        short8 ah0 = *(const short8*)(const void*)(pa0h + k0);
        short8 al0 = *(const short8*)(const void*)(pa0l + k0);
        short8 ah1 = *(const short8*)(const void*)(pa1h + k0);
        short8 al1 = *(const short8*)(const void*)(pa1l + k0);
#pragma unroll
        for (int ct = 0; ct < 14; ++ct) {
            size_t boff = (size_t)(ct * 16 + lrow) * LDA + q * 8 + k0;
            short8 bh = *(const short8*)(const void*)(WT_hi + boff);
            short8 bl = *(const short8*)(const void*)(WT_lo + boff);
            acc0[ct] = mfma16(ah0, bh, acc0[ct]);
            acc0[ct] = mfma16(ah0, bl, acc0[ct]);
            acc0[ct] = mfma16(al0, bh, acc0[ct]);
            acc1[ct] = mfma16(ah1, bh, acc1[ct]);
            acc1[ct] = mfma16(ah1, bl, acc1[ct]);
            acc1[ct] = mfma16(al1, bh, acc1[ct]);
        }
    }

    // epilogue: C/D layout col = ct*16 + lrow, row = base + q*4 + r
    float pv0[4], pv1[4];
#pragma unroll
    for (int r = 0; r < 4; ++r) {
        int r0 = rt + q * 4 + r;
        int r1 = r0 + 16;
        pv0[r] = (r0 < N_NODES) ? post[r0] : 0.f;
        pv1[r] = (r1 < N_NODES) ? post[r1] : 0.f;
    }
#pragma unroll
    for (int ct = 0; ct < 14; ++ct) {
        int col = ct * 16 + lrow;
        if (col >= 220) continue;
        float bv = bias[col];
#pragma unroll
        for (int r = 0; r < 4; ++r) {
            int r0 = rt + q * 4 + r;
            int r1 = r0 + 16;
            if (r0 < N_NODES)
                out[(size_t)r0 * HSTR + col] = pv0[r] * fast_tanh(acc0[ct][r] + bv);
            if (r1 < N_NODES)
                out[(size_t)r1 * HSTR + col] = pv1[r] * fast_tanh(acc1[ct][r] + bv);
        }
    }
}

// tmp10 = h @ W3 — thread per node, full row (h stride HSTR). W3 reads wave-uniform.
__global__ __launch_bounds__(256) void k_w3(const float* __restrict__ h,
                                            const float* __restrict__ W3,
                                            float* __restrict__ tmp) {
    int n = blockIdx.x * 256 + threadIdx.x;
    if (n >= N_NODES) return;
    float a[10];
#pragma unroll
    for (int j = 0; j < 10; ++j) a[j] = 0.f;
    const float4* hr = (const float4*)&h[(size_t)n * HSTR];
#pragma unroll 5
    for (int k4 = 0; k4 < 55; ++k4) {
        float4 v = hr[k4];
        const float* wk = &W3[k4 * 40];
#pragma unroll
        for (int j = 0; j < 10; ++j)
            a[j] += v.x * wk[j] + v.y * wk[10 + j] + v.z * wk[20 + j] + v.w * wk[30 + j];
    }
#pragma unroll
    for (int j2 = 0; j2 < 5; ++j2) {
        float2 o = {a[2 * j2], a[2 * j2 + 1]};
        *(float2*)&tmp[(size_t)n * 10 + j2 * 2] = o;
    }
}

// ---------------- launch ----------------

extern "C" void kernel_launch(void* const* d_in, const int* in_sizes, int n_in,
                              void* d_out, int out_size, void* d_ws, size_t ws_size,
                              hipStream_t stream) {
    const float* x  = (const float*)d_in[0];
    const float* W0 = (const float*)d_in[1];
    const float* b0 = (const float*)d_in[2];
    const float* W1 = (const float*)d_in[3];
    const float* b1 = (const float*)d_in[4];
    const float* W2 = (const float*)d_in[5];
    const float* b2 = (const float*)d_in[6];
    const float* W3 = (const float*)d_in[7];
    const float* b3 = (const float*)d_in[8];
    const int*   ei = (const int*)d_in[9];
    float* out = (float*)d_out;

    int* ws = (int*)d_ws;
    // word offsets (wt1/wt2 = 224*224 ushorts = 25088 WORDS each)
    int* ecsbuf     = ws + 0;               // 50432 (50178 used; [0]=0)
    int* deg_out    = ws + 50432;           // 50176
    int* bsumA      = ws + 100608;          // 256 (196 used)
    float* inv_out  = (float*)(ws + 100864);
    float* inv_in   = (float*)(ws + 151040);
    int* src_sorted = ws + 201216;          // 800000
    unsigned short* wt0h = (unsigned short*)(ws + 1001216);   // 3584 w
    unsigned short* wt0l = (unsigned short*)(ws + 1004800);   // 3584 w
    unsigned short* wt1h = (unsigned short*)(ws + 1008384);   // 25088 w
    unsigned short* wt1l = (unsigned short*)(ws + 1033472);   // 25088 w
    unsigned short* wt2h = (unsigned short*)(ws + 1058560);   // 25088 w
    unsigned short* wt2l = (unsigned short*)(ws + 1083648);   // 25088 w
    unsigned short* ahi  = (unsigned short*)(ws + 1108736);   // 5619712 w
    unsigned short* alo  = (unsigned short*)(ws + 6728448);   // 5619712 w
    float* hbuf  = (float*)(ws + 12348160); // 50000*HSTR = 11200000 w -> end 23548160 (94.2 MB)
    // aliases inside ahi (ahi not yet live / dead by then):
    int* rank    = (int*)ahi;                           // [0, 800000) words of ahi slot
    float* xs    = (float*)(ws + 1108736 + 3000000);    // clear of rank & A22 region
    float* tmp10 = (float*)ahi;                         // layer 3

    // zero ecsbuf + deg_out (contiguous)
    hipMemsetAsync(ws, 0, (size_t)100608 * sizeof(int), stream);

    // CSR hist(+rank) fused with weight splits
    k_hist_wsplit<<<3545, 256, 0, stream>>>(ei, deg_out, ecsbuf, rank,
                                            W0, W1, W2, wt0h, wt0l, wt1h, wt1l, wt2h, wt2l);
    k_scan1<<<196, 256, 0, stream>>>(ecsbuf + 1, ecsbuf + 1, bsumA, NPAD);
    k_scan_mid<<<1, 256, 0, stream>>>(bsumA, 196);
    k_scan3<<<196, 256, 0, stream>>>(ecsbuf + 1, bsumA, NPAD);
    k_post_scan<<<5470, 256, 0, stream>>>(ei, ecsbuf, rank, deg_out, x,
                                          inv_out, inv_in, src_sorted, xs);

    int gemm_grid = (NPAD + 127) / 128;      // 392
    int agg_grid  = (N_NODES + 3) / 4;       // 12500

    // ---- layer 0
    k_agg22_split<<<(N_NODES * 16 + 255) / 256, 256, 0, stream>>>(
        xs, ecsbuf, src_sorted, inv_in, ahi, alo);
    k_gemm_mfma<1, 32><<<gemm_grid, 256, 0, stream>>>(ahi, alo, wt0h, wt0l, b0, inv_out, hbuf);

    // ---- layer 1
    k_agg220_split<<<agg_grid, 256, 0, stream>>>(hbuf, ecsbuf, src_sorted, inv_in, ahi, alo);
    k_gemm_mfma<7, 224><<<gemm_grid, 256, 0, stream>>>(ahi, alo, wt1h, wt1l, b1, inv_out, hbuf);

    // ---- layer 2
    k_agg220_split<<<agg_grid, 256, 0, stream>>>(hbuf, ecsbuf, src_sorted, inv_in, ahi, alo);
    k_gemm_mfma<7, 224><<<gemm_grid, 256, 0, stream>>>(ahi, alo, wt2h, wt2l, b2, inv_out, hbuf);

    // ---- layer 3
    k_w3<<<196, 256, 0, stream>>>(hbuf, W3, tmp10);
    k_agg10_epi<<<(N_NODES * 5 + 255) / 256, 256, 0, stream>>>(
        tmp10, ecsbuf, src_sorted, inv_in, b3, out);
}

// Round 12
// 554.018 us; speedup vs baseline: 1.2799x; 1.0091x over previous
//
#include <hip/hip_runtime.h>
#include <math.h>

#define N_NODES 50000
#define N_EDGES 800000
#define NPAD 50176
#define HSTR 224   // hbuf row stride (floats): exactly 7 aligned 128B lines
// ecsbuf (NPAD+2 ints, ecsbuf[0]=0): counts at ecsbuf[1+d] (k_hist); post-scan
// ecsbuf[1+d] = start(d), never mutated again (rank-based fill).
// Readers: start(n) = ecsbuf[n+1], end(n) = ecsbuf[n+2].

typedef __attribute__((ext_vector_type(8))) short short8;
typedef __attribute__((ext_vector_type(4))) float f32x4;

// ---------------- helpers ----------------

__device__ __forceinline__ float fast_tanh(float x) {
    float e = __expf(2.0f * x);
    float r = __builtin_amdgcn_rcpf(e + 1.0f);
    return 1.0f - 2.0f * r;
}

__device__ __forceinline__ unsigned short rne_bf16(float x) {
    unsigned u = __builtin_bit_cast(unsigned, x);
    return (unsigned short)((u + 0x7FFFu + ((u >> 16) & 1u)) >> 16);
}

__device__ __forceinline__ void split_bf16(float x, unsigned short& hi, unsigned short& lo) {
    hi = rne_bf16(x);
    float hf = __builtin_bit_cast(float, (unsigned)hi << 16);
    lo = rne_bf16(x - hf);
}

__device__ __forceinline__ f32x4 mfma16(short8 a, short8 b, f32x4 c) {
    return __builtin_amdgcn_mfma_f32_16x16x32_bf16(a, b, c, 0, 0, 0);
}

__device__ __forceinline__ void wsplit_one(const float* __restrict__ W, int KIN, int LDA,
                                           unsigned short* __restrict__ WT_hi,
                                           unsigned short* __restrict__ WT_lo, int idx) {
    int n = idx / LDA;
    int k = idx - n * LDA;
    float v = (n < 220 && k < KIN) ? W[k * 220 + n] : 0.f;
    unsigned short hi, lo;
    split_bf16(v, hi, lo);
    WT_hi[idx] = hi;
    WT_lo[idx] = lo;
}

// ---------------- CSR build ----------------

// partitioned launch: [0,3125) histogram + per-edge rank; [3125,3545) weight splits
__global__ void k_hist_wsplit(const int* __restrict__ ei, int* __restrict__ deg_out,
                              int* __restrict__ ecsbuf, int* __restrict__ rank,
                              const float* __restrict__ W0, const float* __restrict__ W1,
                              const float* __restrict__ W2,
                              unsigned short* __restrict__ wt0h, unsigned short* __restrict__ wt0l,
                              unsigned short* __restrict__ wt1h, unsigned short* __restrict__ wt1l,
                              unsigned short* __restrict__ wt2h, unsigned short* __restrict__ wt2l) {
    int bx = blockIdx.x;
    if (bx < 3125) {
        int e = bx * 256 + threadIdx.x;
        if (e < N_EDGES) {
            atomicAdd(&deg_out[ei[e]], 1);
            rank[e] = atomicAdd(&ecsbuf[1 + ei[N_EDGES + e]], 1);
        }
    } else if (bx < 3153) {
        int idx = (bx - 3125) * 256 + threadIdx.x;          // 224*32 = 7168
        if (idx < 224 * 32) wsplit_one(W0, 22, 32, wt0h, wt0l, idx);
    } else if (bx < 3349) {
        int idx = (bx - 3153) * 256 + threadIdx.x;          // 224*224 = 50176
        wsplit_one(W1, 220, 224, wt1h, wt1l, idx);
    } else {
        int idx = (bx - 3349) * 256 + threadIdx.x;
        wsplit_one(W2, 220, 224, wt2h, wt2l, idx);
    }
}

__global__ void k_scan1(const int* __restrict__ in, int* __restrict__ out,
                        int* __restrict__ bsum, int n) {
    __shared__ int s[256];
    int i = blockIdx.x * 256 + threadIdx.x;
    int v = (i < n) ? in[i] : 0;
    s[threadIdx.x] = v;
    __syncthreads();
    for (int off = 1; off < 256; off <<= 1) {
        int t = (threadIdx.x >= off) ? s[threadIdx.x - off] : 0;
        __syncthreads();
        s[threadIdx.x] += t;
        __syncthreads();
    }
    if (i < n) out[i] = s[threadIdx.x] - v;   // exclusive
    if (threadIdx.x == 255 && bsum) bsum[blockIdx.x] = s[255];
}

__global__ void k_scan_mid(int* __restrict__ a, int n) {
    __shared__ int s[256];
    __shared__ int carry;
    if (threadIdx.x == 0) carry = 0;
    for (int base = 0; base < n; base += 256) {
        int i = base + threadIdx.x;
        int v = (i < n) ? a[i] : 0;
        s[threadIdx.x] = v;
        __syncthreads();
        for (int off = 1; off < 256; off <<= 1) {
            int t = (threadIdx.x >= off) ? s[threadIdx.x - off] : 0;
            __syncthreads();
            s[threadIdx.x] += t;
            __syncthreads();
        }
        int c = carry;
        if (i < n) a[i] = s[threadIdx.x] - v + c;
        __syncthreads();
        if (threadIdx.x == 0) carry = c + s[255];
        __syncthreads();
    }
}

__global__ void k_scan3(int* __restrict__ out, const int* __restrict__ bscan, int n) {
    int i = blockIdx.x * 256 + threadIdx.x;
    if (i < n) out[i] += bscan[blockIdx.x];
}

// fused post-scan: [0,196) invsqrt | [196,3321) atomic-free fill | [3321,5470) prescale xs
__global__ void k_post_scan(const int* __restrict__ ei, const int* __restrict__ ecsbuf,
                            const int* __restrict__ rank, const int* __restrict__ deg_out,
                            const float* __restrict__ x,
                            float* __restrict__ inv_out, float* __restrict__ inv_in,
                            int* __restrict__ src_sorted, float* __restrict__ xs) {
    int bx = blockIdx.x;
    if (bx < 196) {
        int n = bx * 256 + threadIdx.x;
        if (n >= N_NODES) return;
        int di = ecsbuf[n + 2] - ecsbuf[n + 1];
        int a = deg_out[n]; if (a < 1) a = 1;
        if (di < 1) di = 1;
        inv_out[n] = 1.0f / sqrtf((float)a);
        inv_in[n]  = 1.0f / sqrtf((float)di);
    } else if (bx < 3321) {
        int e = (bx - 196) * 256 + threadIdx.x;
        if (e < N_EDGES) {
            int d = ei[N_EDGES + e];
            src_sorted[ecsbuf[1 + d] + rank[e]] = ei[e];
        }
    } else {
        int idx = (bx - 3321) * 256 + threadIdx.x;   // n*11 + f2
        if (idx >= N_NODES * 11) return;
        int n = idx / 11;
        int f2 = idx - n * 11;
        int a = deg_out[n]; if (a < 1) a = 1;
        float sc = 1.0f / sqrtf((float)a);
        float2 v = *(const float2*)&x[n * 22 + f2 * 2];
        v.x *= sc; v.y *= sc;
        *(float2*)&xs[n * 22 + f2 * 2] = v;
    }
}

// ---------------- aggregation ----------------

// layer 0: gather pre-scaled xs (width 22), *inv_in, split to bf16 A (K pad 32).
__global__ void k_agg22_split(const float* __restrict__ xs,
                              const int* __restrict__ ecsbuf, const int* __restrict__ srcs,
                              const float* __restrict__ inv_in,
                              unsigned short* __restrict__ A_hi, unsigned short* __restrict__ A_lo) {
    int idx = blockIdx.x * 256 + threadIdx.x;
    int n = idx >> 4, f2 = idx & 15;
    if (n >= N_NODES) return;
    float ax = 0.f, ay = 0.f;
    if (f2 <= 10) {
        const float2* xb = (const float2*)(xs) + f2;
        int e = ecsbuf[n + 1], end = ecsbuf[n + 2];
        for (; e + 3 < end; e += 4) {
            int s0 = srcs[e], s1 = srcs[e + 1], s2 = srcs[e + 2], s3 = srcs[e + 3];
            float2 v0 = xb[s0 * 11], v1 = xb[s1 * 11];
            float2 v2 = xb[s2 * 11], v3 = xb[s3 * 11];
            ax += (v0.x + v1.x) + (v2.x + v3.x);
            ay += (v0.y + v1.y) + (v2.y + v3.y);
        }
        for (; e < end; ++e) {
            float2 v0 = xb[srcs[e] * 11];
            ax += v0.x;
            ay += v0.y;
        }
        float si = inv_in[n];
        ax *= si; ay *= si;
    }
    ushort2 h2, l2;
    split_bf16(ax, h2.x, l2.x);
    split_bf16(ay, h2.y, l2.y);
    *(ushort2*)&A_hi[n * 32 + f2 * 2] = h2;
    *(ushort2*)&A_lo[n * 32 + f2 * 2] = l2;
}

// width-220 gather (h stride HSTR) + *inv_in -> split bf16 A.
// One node per 64-lane group; lanes 0..54 own 4 features; 8 loads in flight.
// ~101 us / 325 MB FETCH = random 7-line-row fetch floor (measured r8/r10/r11).
__global__ __launch_bounds__(256) void k_agg220_split(const float* __restrict__ h,
                                                      const int* __restrict__ ecsbuf,
                                                      const int* __restrict__ srcs,
                                                      const float* __restrict__ inv_in,
                                                      unsigned short* __restrict__ A_hi,
                                                      unsigned short* __restrict__ A_lo) {
    int lane = threadIdx.x & 63;
    int n = blockIdx.x * 4 + (threadIdx.x >> 6);
    if (n >= N_NODES || lane >= 56) return;   // no barriers; early-exit safe
    size_t ob = (size_t)n * 224 + lane * 4;
    if (lane == 55) {                          // K-pad columns 220..223 = 0
        ushort4 z = {0, 0, 0, 0};
        *(ushort4*)&A_hi[ob] = z;
        *(ushort4*)&A_lo[ob] = z;
        return;
    }
    int f4 = lane * 4;
    const float* hb = h + f4;
    int e = ecsbuf[n + 1], end = ecsbuf[n + 2];
    float4 a0 = {0,0,0,0}, a1 = {0,0,0,0}, a2 = {0,0,0,0}, a3 = {0,0,0,0};
    for (; e + 7 < end; e += 8) {
        int s0 = srcs[e],     s1 = srcs[e + 1], s2 = srcs[e + 2], s3 = srcs[e + 3];
        int s4 = srcs[e + 4], s5 = srcs[e + 5], s6 = srcs[e + 6], s7 = srcs[e + 7];
        float4 v0 = *(const float4*)&hb[s0 * HSTR];
        float4 v1 = *(const float4*)&hb[s1 * HSTR];
        float4 v2 = *(const float4*)&hb[s2 * HSTR];
        float4 v3 = *(const float4*)&hb[s3 * HSTR];
        float4 v4 = *(const float4*)&hb[s4 * HSTR];
        float4 v5 = *(const float4*)&hb[s5 * HSTR];
        float4 v6 = *(const float4*)&hb[s6 * HSTR];
        float4 v7 = *(const float4*)&hb[s7 * HSTR];
        a0.x += v0.x; a0.y += v0.y; a0.z += v0.z; a0.w += v0.w;
        a1.x += v1.x; a1.y += v1.y; a1.z += v1.z; a1.w += v1.w;
        a2.x += v2.x; a2.y += v2.y; a2.z += v2.z; a2.w += v2.w;
        a3.x += v3.x; a3.y += v3.y; a3.z += v3.z; a3.w += v3.w;
        a0.x += v4.x; a0.y += v4.y; a0.z += v4.z; a0.w += v4.w;
        a1.x += v5.x; a1.y += v5.y; a1.z += v5.z; a1.w += v5.w;
        a2.x += v6.x; a2.y += v6.y; a2.z += v6.z; a2.w += v6.w;
        a3.x += v7.x; a3.y += v7.y; a3.z += v7.z; a3.w += v7.w;
    }
    for (; e + 3 < end; e += 4) {
        int s0 = srcs[e], s1 = srcs[e + 1], s2 = srcs[e + 2], s3 = srcs[e + 3];
        float4 v0 = *(const float4*)&hb[s0 * HSTR];
        float4 v1 = *(const float4*)&hb[s1 * HSTR];
        float4 v2 = *(const float4*)&hb[s2 * HSTR];
        float4 v3 = *(const float4*)&hb[s3 * HSTR];
        a0.x += v0.x; a0.y += v0.y; a0.z += v0.z; a0.w += v0.w;
        a1.x += v1.x; a1.y += v1.y; a1.z += v1.z; a1.w += v1.w;
        a2.x += v2.x; a2.y += v2.y; a2.z += v2.z; a2.w += v2.w;
        a3.x += v3.x; a3.y += v3.y; a3.z += v3.z; a3.w += v3.w;
    }
    for (; e < end; ++e) {
        float4 v = *(const float4*)&hb[srcs[e] * HSTR];
        a0.x += v.x; a0.y += v.y; a0.z += v.z; a0.w += v.w;
    }
    float sc = inv_in[n];
    float4 t;
    t.x = ((a0.x + a1.x) + (a2.x + a3.x)) * sc;
    t.y = ((a0.y + a1.y) + (a2.y + a3.y)) * sc;
    t.z = ((a0.z + a1.z) + (a2.z + a3.z)) * sc;
    t.w = ((a0.w + a1.w) + (a2.w + a3.w)) * sc;
    ushort4 h4, l4;
    split_bf16(t.x, h4.x, l4.x);
    split_bf16(t.y, h4.y, l4.y);
    split_bf16(t.z, h4.z, l4.z);
    split_bf16(t.w, h4.w, l4.w);
    *(ushort4*)&A_hi[ob] = h4;
    *(ushort4*)&A_lo[ob] = l4;
}

// layer 3: gather tmp10 (width 10, 2 MB -> L2-resident), *inv_in + bias -> d_out
__global__ void k_agg10_epi(const float* __restrict__ tmp, const int* __restrict__ ecsbuf,
                            const int* __restrict__ srcs, const float* __restrict__ inv_in,
                            const float* __restrict__ bias, float* __restrict__ out) {
    int idx = blockIdx.x * 256 + threadIdx.x;
    if (idx >= N_NODES * 5) return;
    int n = idx / 5;
    int f2 = idx - n * 5;
    const float2* tb = (const float2*)(tmp) + f2;
    float ax = 0.f, ay = 0.f;
    int e = ecsbuf[n + 1], end = ecsbuf[n + 2];
    for (; e + 1 < end; e += 2) {
        float2 v0 = tb[srcs[e] * 5];
        float2 v1 = tb[srcs[e + 1] * 5];
        ax += v0.x + v1.x;
        ay += v0.y + v1.y;
    }
    if (e < end) {
        float2 v0 = tb[srcs[e] * 5];
        ax += v0.x;
        ay += v0.y;
    }
    float si = inv_in[n];
    float2 o;
    o.x = ax * si + bias[f2 * 2];
    o.y = ay * si + bias[f2 * 2 + 1];
    *(float2*)&out[n * 10 + f2 * 2] = o;
}

// ---------------- MFMA split-bf16 GEMM, 2 row-tiles per wave ----------------
// D = A@W via A_hi*W_hi + A_hi*W_lo + A_lo*W_hi (~fp32 precision).
// Wave computes 32 rows (two 16-row tiles) sharing B fragments.
// FUSE_W3 (layer 2): h2 never touches memory — per col-tile accumulate
// p10[r][j] += h2 * W3[col][j], 4-step shfl_xor tree over the 16 lanes of each
// row, lane lrow==0 stores tmp[row*10..]. Halves processed sequentially
// (acc0's 4 rows then acc1's) to cap live registers at ~40 over the acc array.
template <int KSTEPS, int LDA, bool FUSE_W3>
__global__ __launch_bounds__(256) void k_gemm_mfma(const unsigned short* __restrict__ A_hi,
                                                   const unsigned short* __restrict__ A_lo,
                                                   const unsigned short* __restrict__ WT_hi,
                                                   const unsigned short* __restrict__ WT_lo,
                                                   const float* __restrict__ bias,
                                                   const float* __restrict__ post,
                                                   float* __restrict__ out,
                                                   const float* __restrict__ W3,
                                                   float* __restrict__ tmp) {
    int tid = threadIdx.x;
    int l = tid & 63, w = tid >> 6;
    int lrow = l & 15, q = l >> 4;
    int rt = blockIdx.x * 128 + w * 32;

    const unsigned short* pa0h = A_hi + (size_t)(rt + lrow) * LDA + q * 8;
    const unsigned short* pa0l = A_lo + (size_t)(rt + lrow) * LDA + q * 8;
    const unsigned short* pa1h = pa0h + 16 * LDA;
    const unsigned short* pa1l = pa0l + 16 * LDA;

    f32x4 acc0[14], acc1[14];
#pragma unroll
    for (int ct = 0; ct < 14; ++ct) {
        acc0[ct] = (f32x4){0.f, 0.f, 0.f, 0.f};
        acc1[ct] = (f32x4){0.f, 0.f, 0.f, 0.f};
    }

#pragma unroll
    for (int ks = 0; ks < KSTEPS; ++ks) {
        int k0 = ks * 32;
        short8 ah0 = *(const short8*)(const void*)(pa0h + k0);
        short8 al0 = *(const short8*)(const void*)(pa0l + k0);
        short8 ah1 = *(const short8*)(const void*)(pa1h + k0);
        short8 al1 = *(const short8*)(const void*)(pa1l + k0);
#pragma unroll
        for (int ct = 0; ct < 14; ++ct) {
            size_t boff = (size_t)(ct * 16 + lrow) * LDA + q * 8 + k0;
            short8 bh = *(const short8*)(const void*)(WT_hi + boff);
            short8 bl = *(const short8*)(const void*)(WT_lo + boff);
            acc0[ct] = mfma16(ah0, bh, acc0[ct]);
            acc0[ct] = mfma16(ah0, bl, acc0[ct]);
            acc0[ct] = mfma16(al0, bh, acc0[ct]);
            acc1[ct] = mfma16(ah1, bh, acc1[ct]);
            acc1[ct] = mfma16(ah1, bl, acc1[ct]);
            acc1[ct] = mfma16(al1, bh, acc1[ct]);
        }
    }

    float pv0[4], pv1[4];
#pragma unroll
    for (int r = 0; r < 4; ++r) {
        int r0 = rt + q * 4 + r;
        int r1 = r0 + 16;
        pv0[r] = (r0 < N_NODES) ? post[r0] : 0.f;
        pv1[r] = (r1 < N_NODES) ? post[r1] : 0.f;
    }

    if (!FUSE_W3) {
#pragma unroll
        for (int ct = 0; ct < 14; ++ct) {
            int col = ct * 16 + lrow;
            if (col >= 220) continue;
            float bv = bias[col];
#pragma unroll
            for (int r = 0; r < 4; ++r) {
                int r0 = rt + q * 4 + r;
                int r1 = r0 + 16;
                if (r0 < N_NODES)
                    out[(size_t)r0 * HSTR + col] = pv0[r] * fast_tanh(acc0[ct][r] + bv);
                if (r1 < N_NODES)
                    out[(size_t)r1 * HSTR + col] = pv1[r] * fast_tanh(acc1[ct][r] + bv);
            }
        }
    } else {
#pragma unroll
        for (int half = 0; half < 2; ++half) {
            const f32x4* acc = half ? acc1 : acc0;
            const float* pv  = half ? pv1 : pv0;
            int rbase = rt + half * 16;
            float p[4][10];
#pragma unroll
            for (int r = 0; r < 4; ++r)
#pragma unroll
                for (int j = 0; j < 10; ++j) p[r][j] = 0.f;
#pragma unroll
            for (int ct = 0; ct < 14; ++ct) {
                int col = ct * 16 + lrow;
                bool cok = col < 220;
                float bv = cok ? bias[col] : 0.f;
                float w3v[10];
                if (cok) {
                    const float2* wp = (const float2*)&W3[col * 10];
#pragma unroll
                    for (int j2 = 0; j2 < 5; ++j2) {
                        float2 t = wp[j2];
                        w3v[2 * j2] = t.x;
                        w3v[2 * j2 + 1] = t.y;
                    }
                } else {
#pragma unroll
                    for (int j = 0; j < 10; ++j) w3v[j] = 0.f;
                }
#pragma unroll
                for (int r = 0; r < 4; ++r) {
                    float h2 = pv[r] * fast_tanh(acc[ct][r] + bv);
#pragma unroll
                    for (int j = 0; j < 10; ++j) p[r][j] += h2 * w3v[j];
                }
            }
            // reduce over the 16 lanes (same q) sharing each row
#pragma unroll
            for (int r = 0; r < 4; ++r)
#pragma unroll
                for (int j = 0; j < 10; ++j) {
                    float v = p[r][j];
                    v += __shfl_xor(v, 1, 64);
                    v += __shfl_xor(v, 2, 64);
                    v += __shfl_xor(v, 4, 64);
                    v += __shfl_xor(v, 8, 64);
                    p[r][j] = v;
                }
            if (lrow == 0) {
#pragma unroll
                for (int r = 0; r < 4; ++r) {
                    int row = rbase + q * 4 + r;
                    if (row < N_NODES) {
#pragma unroll
                        for (int j2 = 0; j2 < 5; ++j2) {
                            float2 o = {p[r][2 * j2], p[r][2 * j2 + 1]};
                            *(float2*)&tmp[(size_t)row * 10 + 2 * j2] = o;
                        }
                    }
                }
            }
        }
    }
}

// ---------------- launch ----------------

extern "C" void kernel_launch(void* const* d_in, const int* in_sizes, int n_in,
                              void* d_out, int out_size, void* d_ws, size_t ws_size,
                              hipStream_t stream) {
    const float* x  = (const float*)d_in[0];
    const float* W0 = (const float*)d_in[1];
    const float* b0 = (const float*)d_in[2];
    const float* W1 = (const float*)d_in[3];
    const float* b1 = (const float*)d_in[4];
    const float* W2 = (const float*)d_in[5];
    const float* b2 = (const float*)d_in[6];
    const float* W3 = (const float*)d_in[7];
    const float* b3 = (const float*)d_in[8];
    const int*   ei = (const int*)d_in[9];
    float* out = (float*)d_out;

    int* ws = (int*)d_ws;
    // word offsets (wt1/wt2 = 224*224 ushorts = 25088 WORDS each)
    int* ecsbuf     = ws + 0;               // 50432 (50178 used; [0]=0)
    int* deg_out    = ws + 50432;           // 50176
    int* bsumA      = ws + 100608;          // 256 (196 used)
    float* inv_out  = (float*)(ws + 100864);
    float* inv_in   = (float*)(ws + 151040);
    int* src_sorted = ws + 201216;          // 800000
    unsigned short* wt0h = (unsigned short*)(ws + 1001216);   // 3584 w
    unsigned short* wt0l = (unsigned short*)(ws + 1004800);   // 3584 w
    unsigned short* wt1h = (unsigned short*)(ws + 1008384);   // 25088 w
    unsigned short* wt1l = (unsigned short*)(ws + 1033472);   // 25088 w
    unsigned short* wt2h = (unsigned short*)(ws + 1058560);   // 25088 w
    unsigned short* wt2l = (unsigned short*)(ws + 1083648);   // 25088 w
    unsigned short* ahi  = (unsigned short*)(ws + 1108736);   // 5619712 w
    unsigned short* alo  = (unsigned short*)(ws + 6728448);   // 5619712 w
    float* hbuf  = (float*)(ws + 12348160); // 50000*HSTR = 11200000 w
    float* tmp10 = (float*)(ws + 23548160); // 500000 w -> end 24048160 (96.2 MB)
    // aliases inside ahi (ahi not yet live at those times):
    int* rank    = (int*)ahi;                           // [0, 800000) words of ahi slot
    float* xs    = (float*)(ws + 1108736 + 3000000);    // clear of rank & A22 region

    // zero ecsbuf + deg_out (contiguous)
    hipMemsetAsync(ws, 0, (size_t)100608 * sizeof(int), stream);

    // CSR hist(+rank) fused with weight splits
    k_hist_wsplit<<<3545, 256, 0, stream>>>(ei, deg_out, ecsbuf, rank,
                                            W0, W1, W2, wt0h, wt0l, wt1h, wt1l, wt2h, wt2l);
    k_scan1<<<196, 256, 0, stream>>>(ecsbuf + 1, ecsbuf + 1, bsumA, NPAD);
    k_scan_mid<<<1, 256, 0, stream>>>(bsumA, 196);
    k_scan3<<<196, 256, 0, stream>>>(ecsbuf + 1, bsumA, NPAD);
    k_post_scan<<<5470, 256, 0, stream>>>(ei, ecsbuf, rank, deg_out, x,
                                          inv_out, inv_in, src_sorted, xs);

    int gemm_grid = (NPAD + 127) / 128;      // 392
    int agg_grid  = (N_NODES + 3) / 4;       // 12500

    // ---- layer 0
    k_agg22_split<<<(N_NODES * 16 + 255) / 256, 256, 0, stream>>>(
        xs, ecsbuf, src_sorted, inv_in, ahi, alo);
    k_gemm_mfma<1, 32, false><<<gemm_grid, 256, 0, stream>>>(
        ahi, alo, wt0h, wt0l, b0, inv_out, hbuf, nullptr, nullptr);

    // ---- layer 1
    k_agg220_split<<<agg_grid, 256, 0, stream>>>(hbuf, ecsbuf, src_sorted, inv_in, ahi, alo);
    k_gemm_mfma<7, 224, false><<<gemm_grid, 256, 0, stream>>>(
        ahi, alo, wt1h, wt1l, b1, inv_out, hbuf, nullptr, nullptr);

    // ---- layer 2 (+ fused W3 projection; h2 never materialized)
    k_agg220_split<<<agg_grid, 256, 0, stream>>>(hbuf, ecsbuf, src_sorted, inv_in, ahi, alo);
    k_gemm_mfma<7, 224, true><<<gemm_grid, 256, 0, stream>>>(
        ahi, alo, wt2h, wt2l, b2, inv_out, nullptr, W3, tmp10);

    // ---- layer 3
    k_agg10_epi<<<(N_NODES * 5 + 255) / 256, 256, 0, stream>>>(
        tmp10, ecsbuf, src_sorted, inv_in, b3, out);
}